// Round 2
// baseline (28004.108 us; speedup 1.0000x reference)
//
#include <hip/hip_runtime.h>
#include <cstdint>
#include <cstddef>

#define L_SEQ   4096
#define BATCH   4
#define DIMM    768
#define D_INNER 1536
#define NHEADS  24
#define HEADDIM 64
#define D_STATE 16
#define CONVD   1568
#define D_IPROJ 3128
#define NPITCH  128

// ---------------------------------------------------------------------------
// Generic f32 GEMM:  C[m,n] = sum_k A[m*lda+k] * W[n*K+k]  (+ bias[n])
// Tiles: 128x128x16, 256 threads, 8x8 microtile per thread.
// ---------------------------------------------------------------------------
#define BM 128
#define BN 128
#define BK 16

__global__ __launch_bounds__(256) void gemm_atw(
    const float* __restrict__ A, int lda,
    const float* __restrict__ W,
    const float* __restrict__ bias,
    float* __restrict__ C, int ldc,
    int M, int N, int K)
{
  __shared__ float As[BK][BM];
  __shared__ float Ws[BK][BN];
  const int tid = threadIdx.x;
  const int m0 = blockIdx.y * BM;
  const int n0 = blockIdx.x * BN;
  const int lr = tid >> 2;          // 0..63 (row within tile)
  const int lk = (tid & 3) << 2;    // 0,4,8,12 (k within tile)
  const int ty = tid >> 4;          // 0..15
  const int tx = tid & 15;          // 0..15

  float acc[8][8];
#pragma unroll
  for (int i = 0; i < 8; ++i)
#pragma unroll
    for (int j = 0; j < 8; ++j) acc[i][j] = 0.f;

  for (int k0 = 0; k0 < K; k0 += BK) {
#pragma unroll
    for (int half = 0; half < 2; ++half) {
      int r = lr + half * 64;
      float4 v = *(const float4*)(A + (size_t)(m0 + r) * lda + k0 + lk);
      As[lk + 0][r] = v.x; As[lk + 1][r] = v.y;
      As[lk + 2][r] = v.z; As[lk + 3][r] = v.w;
    }
#pragma unroll
    for (int half = 0; half < 2; ++half) {
      int r = lr + half * 64;
      int n = n0 + r;
      float4 v = make_float4(0.f, 0.f, 0.f, 0.f);
      if (n < N) v = *(const float4*)(W + (size_t)n * K + k0 + lk);
      Ws[lk + 0][r] = v.x; Ws[lk + 1][r] = v.y;
      Ws[lk + 2][r] = v.z; Ws[lk + 3][r] = v.w;
    }
    __syncthreads();
#pragma unroll
    for (int kk = 0; kk < BK; ++kk) {
      float4 a0 = *(const float4*)&As[kk][ty << 2];
      float4 a1 = *(const float4*)&As[kk][64 + (ty << 2)];
      float4 b0 = *(const float4*)&Ws[kk][tx << 2];
      float4 b1 = *(const float4*)&Ws[kk][64 + (tx << 2)];
      float ar[8] = {a0.x, a0.y, a0.z, a0.w, a1.x, a1.y, a1.z, a1.w};
      float br[8] = {b0.x, b0.y, b0.z, b0.w, b1.x, b1.y, b1.z, b1.w};
#pragma unroll
      for (int i = 0; i < 8; ++i)
#pragma unroll
        for (int j = 0; j < 8; ++j)
          acc[i][j] = fmaf(ar[i], br[j], acc[i][j]);
    }
    __syncthreads();
  }

#pragma unroll
  for (int i = 0; i < 8; ++i) {
    int r = m0 + (ty << 2) + (i & 3) + ((i >> 2) << 6);
#pragma unroll
    for (int j = 0; j < 8; ++j) {
      int c = n0 + (tx << 2) + (j & 3) + ((j >> 2) << 6);
      if (c < N) {
        float v = acc[i][j];
        if (bias) v += bias[c];
        C[(size_t)r * ldc + c] = v;
      }
    }
  }
}

// ---------------------------------------------------------------------------
// dt = softplus(zx[...,3104+h] + dt_bias[h]);  dA = exp(-exp(A_log[h])*dt)
// grid covers MT*NHEADS elements (MT = tokens in chunk)
// ---------------------------------------------------------------------------
__global__ __launch_bounds__(256) void dt_kernel(
    const float* __restrict__ zx, const float* __restrict__ dtb,
    const float* __restrict__ alog, float* __restrict__ dtp,
    float* __restrict__ dap, int total)
{
  int idx = blockIdx.x * 256 + threadIdx.x;
  if (idx >= total) return;
  int bl = idx / NHEADS, hh = idx - bl * NHEADS;
  float raw = zx[(size_t)bl * D_IPROJ + (D_INNER + CONVD) + hh] + dtb[hh];
  float sp = (raw > 20.f) ? raw : log1pf(expf(raw));
  dtp[idx] = sp;
  dap[idx] = expf(-expf(alog[hh]) * sp);
}

// ---------------------------------------------------------------------------
// Depthwise causal conv(4) over L + bias + silu.  Reads zx cols 1536..3103.
// ---------------------------------------------------------------------------
__global__ __launch_bounds__(256) void conv_kernel(
    const float* __restrict__ zx, const float* __restrict__ cw,
    const float* __restrict__ cb, float* __restrict__ xbc)
{
  int idx = blockIdx.x * 256 + threadIdx.x;
  int bl = idx / CONVD;
  int c = idx - bl * CONVD;
  int l = bl & (L_SEQ - 1);   // position within its batch
  float acc = cb[c];
#pragma unroll
  for (int k = 0; k < 4; ++k) {
    int ls = l - 3 + k;
    if (ls >= 0)
      acc = fmaf(cw[c * 4 + k], zx[(size_t)(bl - 3 + k) * D_IPROJ + D_INNER + c], acc);
  }
  xbc[(size_t)bl * CONVD + c] = acc / (1.f + expf(-acc));  // silu
}

// ---------------------------------------------------------------------------
// SSM scan: one wave per (b,h). lane = p. 16 states per lane in registers.
// y (incl. D*x term) overwrites xs region of xbc in place.
// grid.x = nb*NHEADS; buffers are chunk-local.
// ---------------------------------------------------------------------------
#define CL 128
__global__ __launch_bounds__(64) void scan_kernel(
    float* __restrict__ xbc, const float* __restrict__ dtp,
    const float* __restrict__ dap, const float* __restrict__ Dv)
{
  __shared__ float sx[CL][64];
  __shared__ float sbc[CL][32];
  __shared__ float sdt[CL];
  __shared__ float sda[CL];
  const int lane = threadIdx.x;
  const int b = blockIdx.x / NHEADS;
  const int h = blockIdx.x - b * NHEADS;
  const float Dh = Dv[h];
  float hs[16];
#pragma unroll
  for (int n = 0; n < 16; ++n) hs[n] = 0.f;

  for (int l0 = 0; l0 < L_SEQ; l0 += CL) {
    const int bl0 = b * L_SEQ + l0;
    for (int i = lane; i < CL * 16; i += 64) {
      int t = i >> 4, q = (i & 15) << 2;
      float4 v = *(const float4*)&xbc[(size_t)(bl0 + t) * CONVD + h * HEADDIM + q];
      *(float4*)&sx[t][q] = v;
    }
    for (int i = lane; i < CL * 8; i += 64) {
      int t = i >> 3, q = (i & 7) << 2;
      float4 v = *(const float4*)&xbc[(size_t)(bl0 + t) * CONVD + D_INNER + q];
      *(float4*)&sbc[t][q] = v;
    }
    for (int i = lane; i < CL; i += 64) {
      sdt[i] = dtp[(size_t)(bl0 + i) * NHEADS + h];
      sda[i] = dap[(size_t)(bl0 + i) * NHEADS + h];
    }
    __syncthreads();
    for (int t = 0; t < CL; ++t) {
      float dav = sda[t], dtv = sdt[t];
      float xv = sx[t][lane];
      float coef = dtv * xv;
      float y0 = 0.f, y1 = 0.f, y2 = 0.f, y3 = 0.f;
#pragma unroll
      for (int n = 0; n < 16; ++n) {
        float hv = fmaf(hs[n], dav, coef * sbc[t][n]);
        hs[n] = hv;
        float cv = sbc[t][16 + n];
        if ((n & 3) == 0)      y0 = fmaf(hv, cv, y0);
        else if ((n & 3) == 1) y1 = fmaf(hv, cv, y1);
        else if ((n & 3) == 2) y2 = fmaf(hv, cv, y2);
        else                   y3 = fmaf(hv, cv, y3);
      }
      float yv = fmaf(Dh, xv, (y0 + y1) + (y2 + y3));
      xbc[(size_t)(bl0 + t) * CONVD + h * HEADDIM + lane] = yv;
    }
    __syncthreads();
  }
}

// ---------------------------------------------------------------------------
// y *= silu(z); RMS-norm over 1536; * norm_w.  In place on xbc (stride 1568).
// ---------------------------------------------------------------------------
__global__ __launch_bounds__(256) void norm_kernel(
    float* __restrict__ y, const float* __restrict__ zx,
    const float* __restrict__ nw)
{
  const int row = blockIdx.x;
  const int tid = threadIdx.x;
  float* yr = y + (size_t)row * CONVD;
  const float* zr = zx + (size_t)row * D_IPROJ;
  float v[6];
  float ss = 0.f;
#pragma unroll
  for (int jj = 0; jj < 6; ++jj) {
    int c = jj * 256 + tid;
    float yv = yr[c];
    float zv = zr[c];
    float sz = zv / (1.f + expf(-zv));
    float val = yv * sz;
    v[jj] = val;
    ss = fmaf(val, val, ss);
  }
#pragma unroll
  for (int off = 32; off > 0; off >>= 1) ss += __shfl_xor(ss, off, 64);
  __shared__ float red[4];
  if ((tid & 63) == 0) red[tid >> 6] = ss;
  __syncthreads();
  float tot = red[0] + red[1] + red[2] + red[3];
  float rs = rsqrtf(tot * (1.f / 1536.f) + 1e-5f);
#pragma unroll
  for (int jj = 0; jj < 6; ++jj) {
    int c = jj * 256 + tid;
    yr[c] = v[jj] * rs * nw[c];
  }
}

// ---------------------------------------------------------------------------
// sigmoid (except velocity) + type mask, in place on d_out (full tensor).
// ---------------------------------------------------------------------------
__global__ __launch_bounds__(256) void epilogue_kernel(
    float* __restrict__ out, const int* __restrict__ tids)
{
  int idx = blockIdx.x * 256 + threadIdx.x;  // < 8*16384*128
  int j = idx >> 21;
  int rem = idx & ((1 << 21) - 1);
  int bl = rem >> 7;
  float vv = out[idx];
  if (j & 3) vv = 1.f / (1.f + expf(-vv));
  int want = j >> 2;
  vv = (tids[bl] == want) ? vv : 0.f;
  out[idx] = vv;
}

// ---------------------------------------------------------------------------
extern "C" void kernel_launch(void* const* d_in, const int* in_sizes, int n_in,
                              void* d_out, int out_size, void* d_ws, size_t ws_size,
                              hipStream_t stream)
{
  const float* x_in = (const float*)d_in[0];
  const int*   tids = (const int*)d_in[1];
  const float* ipw  = (const float*)d_in[2];
  const float* cw   = (const float*)d_in[3];
  const float* cb   = (const float*)d_in[4];
  const float* dtb  = (const float*)d_in[5];
  const float* alog = (const float*)d_in[6];
  const float* Dv   = (const float*)d_in[7];
  const float* nw   = (const float*)d_in[8];
  const float* opw  = (const float*)d_in[9];
  const float* hw   = (const float*)d_in[10];
  const float* hb   = (const float*)d_in[11];
  const float* how  = (const float*)d_in[12];
  const float* hob  = (const float*)d_in[13];
  float* out = (float*)d_out;

  // Footprint per batch (floats): xcur 3.15M + zx 12.81M + xbc 6.42M + dt/dA 0.20M
  const size_t PB_XCUR = (size_t)L_SEQ * DIMM;      // 3,145,728
  const size_t PB_ZX   = (size_t)L_SEQ * D_IPROJ;   // 12,812,288
  const size_t PB_XBC  = (size_t)L_SEQ * CONVD;     // 6,422,528
  const size_t PB_DT   = (size_t)L_SEQ * NHEADS;    //    98,304
  const size_t PB_ALL  = PB_XCUR + PB_ZX + PB_XBC + 2 * PB_DT; // 22,577,152

  // Largest batch-chunk that fits the workspace actually provided.
  int nb = 4;
  while (nb > 1 && (size_t)nb * PB_ALL * sizeof(float) > ws_size) nb >>= 1;

  static const int wmap[4] = {0, 3, 1, 2};  // velocity, frames, onset, offset

  for (int b0 = 0; b0 < BATCH; b0 += nb) {
    const int MT = nb * L_SEQ;          // tokens in this chunk
    float* ws   = (float*)d_ws;
    float* xcur = ws;
    float* zx   = xcur + (size_t)nb * PB_XCUR;
    float* xbc  = zx   + (size_t)nb * PB_ZX;
    float* dtp  = xbc  + (size_t)nb * PB_XBC;
    float* dap  = dtp  + (size_t)nb * PB_DT;
    float* Hbuf = zx;                   // alias: zx dead at head stage

    for (int i = 0; i < 6; ++i) {
      const float* A = (i == 0) ? (x_in + (size_t)b0 * L_SEQ * DIMM) : xcur;
      gemm_atw<<<dim3((D_IPROJ + BN - 1) / BN, MT / BM), 256, 0, stream>>>(
          A, DIMM, ipw + (size_t)i * D_IPROJ * DIMM, nullptr, zx, D_IPROJ,
          MT, D_IPROJ, DIMM);
      dt_kernel<<<(MT * NHEADS + 255) / 256, 256, 0, stream>>>(
          zx, dtb + i * NHEADS, alog + i * NHEADS, dtp, dap, MT * NHEADS);
      conv_kernel<<<(MT * CONVD + 255) / 256, 256, 0, stream>>>(
          zx, cw + (size_t)i * CONVD * 4, cb + i * CONVD, xbc);
      scan_kernel<<<nb * NHEADS, 64, 0, stream>>>(
          xbc, dtp, dap, Dv + i * NHEADS);
      norm_kernel<<<MT, 256, 0, stream>>>(xbc, zx, nw + i * D_INNER);
      gemm_atw<<<dim3(DIMM / BN, MT / BM), 256, 0, stream>>>(
          xbc, CONVD, opw + (size_t)i * DIMM * D_INNER, nullptr, xcur, DIMM,
          MT, DIMM, D_INNER);
    }

    for (int t = 0; t < 2; ++t) {
      gemm_atw<<<dim3(DIMM / BN, MT / BM), 256, 0, stream>>>(
          xcur, DIMM, hw + (size_t)t * DIMM * DIMM, hb + t * DIMM, Hbuf, DIMM,
          MT, DIMM, DIMM);
      for (int q = 0; q < 4; ++q) {
        int j = t * 4 + q;
        int widx = wmap[q];
        gemm_atw<<<dim3(1, MT / BM), 256, 0, stream>>>(
            Hbuf, DIMM, how + (size_t)(t * 4 + widx) * NPITCH * DIMM,
            hob + (t * 4 + widx) * NPITCH,
            out + (size_t)j * (BATCH * L_SEQ) * NPITCH + (size_t)b0 * L_SEQ * NPITCH,
            NPITCH, MT, NPITCH, DIMM);
      }
    }
  }

  epilogue_kernel<<<(8 * BATCH * L_SEQ * NPITCH) / 256, 256, 0, stream>>>(out, tids);
}

// Round 4
// 8371.886 us; speedup vs baseline: 3.3450x; 3.3450x over previous
//
#include <hip/hip_runtime.h>
#include <cstdint>
#include <cstddef>

#define L_SEQ   4096
#define BATCH   4
#define DIMM    768
#define D_INNER 1536
#define NHEADS  24
#define HEADDIM 64
#define D_STATE 16
#define CONVD   1568
#define D_IPROJ 3128
#define NPITCH  128
#define SEGLEN  64
#define NSEG    (L_SEQ / SEGLEN)   // 64

typedef _Float16 f16x8 __attribute__((ext_vector_type(8)));
typedef _Float16 f16x4 __attribute__((ext_vector_type(4)));
typedef float    f32x4 __attribute__((ext_vector_type(4)));

// ---------------------------------------------------------------------------
// f16 MFMA GEMM: C[m,n] = sum_k A[m*lda+k]*W[n*K+k] (+bias). 128x128x64 tile,
// 256 thr = 4 waves (2x2), each wave 64x64 via 4x4 frags of 16x16x32 MFMA.
// OM: 0 = f32 out (col<N guard), 1 = f16 out, 2 = f16 out + bias,
//     3 = f32 out + bias + head-slot permute (addr = q*extra + row*128 + col%128)
// ---------------------------------------------------------------------------
#define LDSP 72   // 64 + 8 halfwords pad (16B) -> 2-way-only LDS aliasing

template <int OM>
__global__ __launch_bounds__(256, 2) void gemm_mfma(
    const _Float16* __restrict__ A, int lda,
    const _Float16* __restrict__ W,
    const float* __restrict__ bias,
    void* __restrict__ Cv, long ldc, long extra,
    int M, int N, int K)
{
  __shared__ _Float16 As[128 * LDSP];
  __shared__ _Float16 Ws[128 * LDSP];
  const int tid = threadIdx.x;
  const int lane = tid & 63, wid = tid >> 6;
  const int wr = wid >> 1, wc = wid & 1;
  const long m0 = (long)blockIdx.y * 128;
  const int n0 = blockIdx.x * 128;

  uint4 areg[4], breg[4];

  auto loadA = [&](int k0) {
#pragma unroll
    for (int p = 0; p < 4; ++p) {
      int id = p * 256 + tid;
      int row = id >> 3, kc = id & 7;
      areg[p] = *(const uint4*)(A + (m0 + row) * (long)lda + k0 + kc * 8);
    }
  };
  auto loadB = [&](int k0) {
#pragma unroll
    for (int p = 0; p < 4; ++p) {
      int id = p * 256 + tid;
      int row = id >> 3, kc = id & 7;
      int n = n0 + row;
      uint4 z; z.x = z.y = z.z = z.w = 0u;
      breg[p] = (n < N) ? *(const uint4*)(W + (long)n * K + k0 + kc * 8) : z;
    }
  };
  auto stage = [&]() {
#pragma unroll
    for (int p = 0; p < 4; ++p) {
      int id = p * 256 + tid;
      int row = id >> 3, kc = id & 7;
      *(uint4*)&As[row * LDSP + kc * 8] = areg[p];
      *(uint4*)&Ws[row * LDSP + kc * 8] = breg[p];
    }
  };

  f32x4 acc[4][4] = {};
  loadA(0); loadB(0);
  const int la = lane & 15, lg = lane >> 4;

  for (int k0 = 0;;) {
    __syncthreads();
    stage();
    __syncthreads();
    int kn = k0 + 64;
    if (kn < K) { loadA(kn); loadB(kn); }
#pragma unroll
    for (int ks = 0; ks < 2; ++ks) {
      f16x8 af[4], bfr[4];
#pragma unroll
      for (int i = 0; i < 4; ++i) {
        af[i]  = *(const f16x8*)&As[(wr * 64 + i * 16 + la) * LDSP + ks * 32 + lg * 8];
        bfr[i] = *(const f16x8*)&Ws[(wc * 64 + i * 16 + la) * LDSP + ks * 32 + lg * 8];
      }
#pragma unroll
      for (int i = 0; i < 4; ++i)
#pragma unroll
        for (int j = 0; j < 4; ++j)
          acc[i][j] = __builtin_amdgcn_mfma_f32_16x16x32_f16(af[i], bfr[j], acc[i][j], 0, 0, 0);
    }
    k0 = kn;
    if (k0 >= K) break;
  }

#pragma unroll
  for (int i = 0; i < 4; ++i) {
    long rbase = m0 + wr * 64 + i * 16 + lg * 4;
#pragma unroll
    for (int j = 0; j < 4; ++j) {
      int col = n0 + wc * 64 + j * 16 + la;
#pragma unroll
      for (int r = 0; r < 4; ++r) {
        long row = rbase + r;
        float v = acc[i][j][r];
        if (OM == 0) {
          if (col < N) ((float*)Cv)[row * ldc + col] = v;
        } else if (OM == 1) {
          ((_Float16*)Cv)[row * ldc + col] = (_Float16)v;
        } else if (OM == 2) {
          ((_Float16*)Cv)[row * ldc + col] = (_Float16)(v + bias[col]);
        } else {
          long q = col >> 7;
          ((float*)Cv)[q * extra + row * 128 + (col & 127)] = v + bias[col];
        }
      }
    }
  }
}

// ---------------------------------------------------------------------------
__global__ __launch_bounds__(256) void cvt_kernel(
    const float* __restrict__ src, _Float16* __restrict__ dst, long n4)
{
  long i = (long)blockIdx.x * 256 + threadIdx.x;
  long stride = (long)gridDim.x * 256;
  for (; i < n4; i += stride) {
    float4 v = *(const float4*)(src + i * 4);
    f16x4 o = { (_Float16)v.x, (_Float16)v.y, (_Float16)v.z, (_Float16)v.w };
    *(f16x4*)(dst + i * 4) = o;
  }
}

// how [2][4][128][768] -> packed [2][512][768] in output order; hob likewise.
__global__ __launch_bounds__(256) void pack_head_kernel(
    const float* __restrict__ how, const float* __restrict__ hob,
    _Float16* __restrict__ howb, float* __restrict__ hobp)
{
  const int wmap[4] = {0, 3, 1, 2};
  int idx = blockIdx.x * 256 + threadIdx.x;
  if (idx < 2 * 512 * 768) {
    int t = idx / (512 * 768);
    int rem = idx - t * 512 * 768;
    int q = rem / (128 * 768);
    int rem2 = rem - q * 128 * 768;
    howb[idx] = (_Float16)how[((size_t)(t * 4 + wmap[q])) * 128 * 768 + rem2];
  }
  if (idx < 1024) {
    int t = idx >> 9, rem = idx & 511;
    int q = rem >> 7, pp = rem & 127;
    hobp[idx] = hob[(t * 4 + wmap[q]) * 128 + pp];
  }
}

// ---------------------------------------------------------------------------
__global__ __launch_bounds__(256) void dt_kernel(
    const float* __restrict__ zx, const float* __restrict__ dtb,
    const float* __restrict__ alog, float* __restrict__ dtp,
    float* __restrict__ dap, int total)
{
  int idx = blockIdx.x * 256 + threadIdx.x;
  if (idx >= total) return;
  int bl = idx / NHEADS, hh = idx - bl * NHEADS;
  float raw = zx[(size_t)bl * D_IPROJ + (D_INNER + CONVD) + hh] + dtb[hh];
  float sp = (raw > 20.f) ? raw : log1pf(expf(raw));
  dtp[idx] = sp;
  dap[idx] = expf(-expf(alog[hh]) * sp);
}

__global__ __launch_bounds__(256) void conv_kernel(
    const float* __restrict__ zx, const float* __restrict__ cw,
    const float* __restrict__ cb, float* __restrict__ xbc)
{
  int idx = blockIdx.x * 256 + threadIdx.x;
  int bl = idx / CONVD;
  int c = idx - bl * CONVD;
  int l = bl & (L_SEQ - 1);
  float acc = cb[c];
#pragma unroll
  for (int k = 0; k < 4; ++k) {
    int ls = l - 3 + k;
    if (ls >= 0)
      acc = fmaf(cw[c * 4 + k], zx[(size_t)(bl - 3 + k) * D_IPROJ + D_INNER + c], acc);
  }
  xbc[(size_t)bl * CONVD + c] = acc / (1.f + expf(-acc));
}

// ---------------------------------------------------------------------------
// Scan pass A: per (b,h,seg) local scan (h0=0). Writes y_local (+D*x) in place,
// inclusive cumprod into cumq[bh][l], final local state into Hseg slot.
// ---------------------------------------------------------------------------
__global__ __launch_bounds__(64) void scanA_kernel(
    float* __restrict__ xbc, const float* __restrict__ dtp,
    const float* __restrict__ dap, const float* __restrict__ Dv,
    float* __restrict__ Hseg, float* __restrict__ cumq)
{
  __shared__ float sx[SEGLEN][64];
  __shared__ float sbc[SEGLEN][32];
  __shared__ float sdt[SEGLEN], sda[SEGLEN], scp[SEGLEN];
  const int lane = threadIdx.x;
  const int seg = blockIdx.x & (NSEG - 1);
  const int bh = blockIdx.x >> 6;
  const int h = bh % NHEADS, b = bh / NHEADS;
  const float Dh = Dv[h];
  const int bl0 = b * L_SEQ + seg * SEGLEN;

  for (int i = lane; i < SEGLEN * 16; i += 64) {
    int t = i >> 4, q = (i & 15) << 2;
    *(float4*)&sx[t][q] = *(const float4*)&xbc[(size_t)(bl0 + t) * CONVD + h * HEADDIM + q];
  }
  for (int i = lane; i < SEGLEN * 8; i += 64) {
    int t = i >> 3, q = (i & 7) << 2;
    *(float4*)&sbc[t][q] = *(const float4*)&xbc[(size_t)(bl0 + t) * CONVD + D_INNER + q];
  }
  sdt[lane] = dtp[(size_t)(bl0 + lane) * NHEADS + h];
  sda[lane] = dap[(size_t)(bl0 + lane) * NHEADS + h];
  __syncthreads();

  float hs[16];
#pragma unroll
  for (int n = 0; n < 16; ++n) hs[n] = 0.f;
  float cp = 1.f;

  for (int t = 0; t < SEGLEN; ++t) {
    float dav = sda[t], dtv = sdt[t], xv = sx[t][lane];
    cp *= dav;
    if (lane == 0) scp[t] = cp;
    float coef = dtv * xv;
    float y0 = 0.f, y1 = 0.f, y2 = 0.f, y3 = 0.f;
#pragma unroll
    for (int n = 0; n < 16; ++n) {
      float hv = fmaf(hs[n], dav, coef * sbc[t][n]);
      hs[n] = hv;
      float cvv = sbc[t][16 + n];
      if ((n & 3) == 0)      y0 = fmaf(hv, cvv, y0);
      else if ((n & 3) == 1) y1 = fmaf(hv, cvv, y1);
      else if ((n & 3) == 2) y2 = fmaf(hv, cvv, y2);
      else                   y3 = fmaf(hv, cvv, y3);
    }
    sx[t][lane] = fmaf(Dh, xv, (y0 + y1) + (y2 + y3));
  }
  __syncthreads();

  for (int i = lane; i < SEGLEN * 16; i += 64) {
    int t = i >> 4, q = (i & 15) << 2;
    *(float4*)&xbc[(size_t)(bl0 + t) * CONVD + h * HEADDIM + q] = *(float4*)&sx[t][q];
  }
  float* Hst = Hseg + ((size_t)bh * NSEG + seg) * 1024 + lane * 16;
#pragma unroll
  for (int n = 0; n < 16; n += 4)
    *(float4*)&Hst[n] = make_float4(hs[n], hs[n + 1], hs[n + 2], hs[n + 3]);
  cumq[(size_t)bh * L_SEQ + seg * SEGLEN + lane] = scp[lane];
}

// Pass B: per (b,h) combine across segments; Hseg slot becomes ENTRY state.
__global__ __launch_bounds__(64) void scanB_kernel(
    float* __restrict__ Hseg, const float* __restrict__ cumq)
{
  const int lane = threadIdx.x;
  const int bh = blockIdx.x;
  float hin[16];
#pragma unroll
  for (int n = 0; n < 16; ++n) hin[n] = 0.f;
  for (int s = 0; s < NSEG; ++s) {
    float* slot = Hseg + ((size_t)bh * NSEG + s) * 1024 + lane * 16;
    float P = cumq[(size_t)bh * L_SEQ + s * SEGLEN + (SEGLEN - 1)];
    float hl[16];
#pragma unroll
    for (int n = 0; n < 16; n += 4) {
      float4 v = *(float4*)(slot + n);
      hl[n] = v.x; hl[n + 1] = v.y; hl[n + 2] = v.z; hl[n + 3] = v.w;
    }
#pragma unroll
    for (int n = 0; n < 16; n += 4)
      *(float4*)(slot + n) = make_float4(hin[n], hin[n + 1], hin[n + 2], hin[n + 3]);
#pragma unroll
    for (int n = 0; n < 16; ++n) hin[n] = fmaf(P, hin[n], hl[n]);
  }
}

// Pass C: y += cumprod * (C . h_entry)
__global__ __launch_bounds__(64) void scanC_kernel(
    float* __restrict__ xbc, const float* __restrict__ Hseg,
    const float* __restrict__ cumq)
{
  const int seg = blockIdx.x & (NSEG - 1);
  if (seg == 0) return;   // entry state is exactly zero
  __shared__ float sc[SEGLEN][16];
  __shared__ float scq[SEGLEN];
  const int lane = threadIdx.x;
  const int bh = blockIdx.x >> 6;
  const int h = bh % NHEADS, b = bh / NHEADS;
  const int bl0 = b * L_SEQ + seg * SEGLEN;
  const float* slot = Hseg + ((size_t)bh * NSEG + seg) * 1024 + lane * 16;
  float hin[16];
#pragma unroll
  for (int n = 0; n < 16; n += 4) {
    float4 v = *(const float4*)(slot + n);
    hin[n] = v.x; hin[n + 1] = v.y; hin[n + 2] = v.z; hin[n + 3] = v.w;
  }
  for (int i = lane; i < SEGLEN * 4; i += 64) {
    int t = i >> 2, q = (i & 3) << 2;
    *(float4*)&sc[t][q] =
        *(const float4*)&xbc[(size_t)(bl0 + t) * CONVD + D_INNER + D_STATE + q];
  }
  scq[lane] = cumq[(size_t)bh * L_SEQ + seg * SEGLEN + lane];
  __syncthreads();
  for (int t = 0; t < SEGLEN; ++t) {
    float dot = 0.f;
#pragma unroll
    for (int n = 0; n < 16; ++n) dot = fmaf(hin[n], sc[t][n], dot);
    size_t ad = (size_t)(bl0 + t) * CONVD + h * HEADDIM + lane;
    xbc[ad] = fmaf(scq[t], dot, xbc[ad]);
  }
}

// ---------------------------------------------------------------------------
// y *= silu(z); RMS-norm over 1536; * norm_w; write f16 into ybf (stride 6256)
// ---------------------------------------------------------------------------
__global__ __launch_bounds__(256) void norm_kernel(
    const float* __restrict__ y, const float* __restrict__ zx,
    const float* __restrict__ nw, _Float16* __restrict__ ybf)
{
  const int row = blockIdx.x;
  const int tid = threadIdx.x;
  const float* yr = y + (size_t)row * CONVD;
  const float* zr = zx + (size_t)row * D_IPROJ;
  float v[6];
  float ss = 0.f;
#pragma unroll
  for (int jj = 0; jj < 6; ++jj) {
    int c = jj * 256 + tid;
    float yv = yr[c];
    float zv = zr[c];
    float sz = zv / (1.f + expf(-zv));
    float val = yv * sz;
    v[jj] = val;
    ss = fmaf(val, val, ss);
  }
#pragma unroll
  for (int off = 32; off > 0; off >>= 1) ss += __shfl_xor(ss, off, 64);
  __shared__ float red[4];
  if ((tid & 63) == 0) red[tid >> 6] = ss;
  __syncthreads();
  float tot = red[0] + red[1] + red[2] + red[3];
  float rs = rsqrtf(tot * (1.f / 1536.f) + 1e-5f);
  _Float16* orow = ybf + (size_t)row * 6256;
#pragma unroll
  for (int jj = 0; jj < 6; ++jj) {
    int c = jj * 256 + tid;
    orow[c] = (_Float16)(v[jj] * rs * nw[c]);
  }
}

__global__ __launch_bounds__(256) void epilogue_kernel(
    float* __restrict__ out, const int* __restrict__ tids)
{
  int idx = blockIdx.x * 256 + threadIdx.x;
  int j = idx >> 21;
  int rem = idx & ((1 << 21) - 1);
  int bl = rem >> 7;
  float vv = out[idx];
  if (j & 3) vv = 1.f / (1.f + expf(-vv));
  int want = j >> 2;
  vv = (tids[bl] == want) ? vv : 0.f;
  out[idx] = vv;
}

// ---------------------------------------------------------------------------
extern "C" void kernel_launch(void* const* d_in, const int* in_sizes, int n_in,
                              void* d_out, int out_size, void* d_ws, size_t ws_size,
                              hipStream_t stream)
{
  const float* x_in = (const float*)d_in[0];
  const int*   tids = (const int*)d_in[1];
  const float* ipw  = (const float*)d_in[2];
  const float* cw   = (const float*)d_in[3];
  const float* cb   = (const float*)d_in[4];
  const float* dtb  = (const float*)d_in[5];
  const float* alog = (const float*)d_in[6];
  const float* Dv   = (const float*)d_in[7];
  const float* nw   = (const float*)d_in[8];
  const float* opw  = (const float*)d_in[9];
  const float* hw   = (const float*)d_in[10];
  const float* hb   = (const float*)d_in[11];
  const float* how  = (const float*)d_in[12];
  const float* hob  = (const float*)d_in[13];
  float* out = (float*)d_out;

  // ---- workspace carve: f16 weights + per-chunk activations ----
  char* p = (char*)d_ws;
  _Float16* ipw_b = (_Float16*)p; p += (size_t)14413824 * 2;  // 6*3128*768
  _Float16* opw_b = (_Float16*)p; p += (size_t)7077888 * 2;   // 6*768*1536
  _Float16* hw_b  = (_Float16*)p; p += (size_t)1179648 * 2;   // 2*768*768
  _Float16* how_b = (_Float16*)p; p += (size_t)786432 * 2;    // 2*512*768
  float*    hob_p = (float*)p;    p += (size_t)1024 * 4;
  const size_t used_w = (size_t)(p - (char*)d_ws);
  const size_t PB = 90701824;  // bytes per batch of chunk buffers
  int nb = 4;
  while (nb > 1 && used_w + (size_t)nb * PB > ws_size) nb >>= 1;

  // ---- weight conversions (idempotent, every launch) ----
  cvt_kernel<<<8192, 256, 0, stream>>>(ipw, ipw_b, 14413824 / 4);
  cvt_kernel<<<6912, 256, 0, stream>>>(opw, opw_b, 7077888 / 4);
  cvt_kernel<<<1152, 256, 0, stream>>>(hw, hw_b, 1179648 / 4);
  pack_head_kernel<<<3072, 256, 0, stream>>>(how, hob, how_b, hob_p);

  for (int b0 = 0; b0 < BATCH; b0 += nb) {
    const int MT = nb * L_SEQ;
    float* zx   = (float*)p;
    float* xbc  = zx + (size_t)MT * D_IPROJ;
    float* Hseg = xbc + (size_t)MT * CONVD;
    float* dtp  = Hseg + (size_t)nb * NHEADS * NSEG * 1024;
    float* dap  = dtp + (size_t)MT * NHEADS;
    float* cumq = dap + (size_t)MT * NHEADS;
    _Float16* xbuf = (_Float16*)(cumq + (size_t)MT * NHEADS);
    _Float16* ybf  = (_Float16*)zx + 3072;   // strided (6256) inside zx rows
    _Float16* Hbf  = (_Float16*)zx;          // head hidden, zx dead then

    cvt_kernel<<<6144, 256, 0, stream>>>(x_in + (size_t)b0 * L_SEQ * DIMM,
                                         xbuf, (long)MT * DIMM / 4);

    for (int i = 0; i < 6; ++i) {
      gemm_mfma<0><<<dim3((D_IPROJ + 127) / 128, MT / 128), 256, 0, stream>>>(
          xbuf, DIMM, ipw_b + (size_t)i * D_IPROJ * DIMM, nullptr,
          zx, D_IPROJ, 0, MT, D_IPROJ, DIMM);
      dt_kernel<<<(MT * NHEADS + 255) / 256, 256, 0, stream>>>(
          zx, dtb + i * NHEADS, alog + i * NHEADS, dtp, dap, MT * NHEADS);
      conv_kernel<<<(MT * CONVD) / 256, 256, 0, stream>>>(
          zx, cw + (size_t)i * CONVD * 4, cb + i * CONVD, xbc);
      scanA_kernel<<<nb * NHEADS * NSEG, 64, 0, stream>>>(
          xbc, dtp, dap, Dv + i * NHEADS, Hseg, cumq);
      scanB_kernel<<<nb * NHEADS, 64, 0, stream>>>(Hseg, cumq);
      scanC_kernel<<<nb * NHEADS * NSEG, 64, 0, stream>>>(xbc, Hseg, cumq);
      norm_kernel<<<MT, 256, 0, stream>>>(xbc, zx, nw + i * D_INNER, ybf);
      gemm_mfma<1><<<dim3(DIMM / 128, MT / 128), 256, 0, stream>>>(
          ybf, 6256, opw_b + (size_t)i * DIMM * D_INNER, nullptr,
          xbuf, DIMM, 0, MT, DIMM, D_INNER);
    }

    for (int t = 0; t < 2; ++t) {
      gemm_mfma<2><<<dim3(DIMM / 128, MT / 128), 256, 0, stream>>>(
          xbuf, DIMM, hw_b + (size_t)t * DIMM * DIMM, hb + t * DIMM,
          Hbf, DIMM, 0, MT, DIMM, DIMM);
      gemm_mfma<3><<<dim3(4, MT / 128), 256, 0, stream>>>(
          Hbf, DIMM, how_b + (size_t)t * 512 * DIMM, hob_p + t * 512,
          out + (size_t)t * 4 * 16384 * 128 + (size_t)b0 * L_SEQ * 128,
          128, (long)16384 * 128, MT, 512, DIMM);
    }
  }

  epilogue_kernel<<<(8 * 16384 * 128) / 256, 256, 0, stream>>>(out, tids);
}

// Round 5
// 7930.314 us; speedup vs baseline: 3.5313x; 1.0557x over previous
//
#include <hip/hip_runtime.h>
#include <cstdint>
#include <cstddef>

#define L_SEQ   4096
#define BATCH   4
#define DIMM    768
#define D_INNER 1536
#define NHEADS  24
#define HEADDIM 64
#define D_STATE 16
#define CONVD   1568
#define D_IPROJ 3128
#define NPITCH  128
#define SEGLEN  64
#define NSEG    (L_SEQ / SEGLEN)   // 64

typedef _Float16 f16x8 __attribute__((ext_vector_type(8)));
typedef _Float16 f16x4 __attribute__((ext_vector_type(4)));
typedef float    f32x4 __attribute__((ext_vector_type(4)));

// ---------------------------------------------------------------------------
// f16 MFMA GEMM: C[m,n] = sum_k A[m*lda+k]*W[n*K+k] (+bias). 128x128x64 tile,
// 4 waves (2x2), 16x16x32 MFMA, XOR-swizzled LDS, LDS-transpose epilogue.
// OM: 0 = f16 out (+ col<N guard), 2 = f16 out + f32 bias,
//     3 = f32 out + bias + sigmoid(q>0) + type-mask (head fusion; N=512)
// ---------------------------------------------------------------------------
template <int OM>
__global__ __launch_bounds__(256, 2) void gemm_mfma(
    const _Float16* __restrict__ A, int lda,
    const _Float16* __restrict__ W,
    const float* __restrict__ bias,
    void* __restrict__ Cv, long ldc, long extra,
    int M, int N, int K,
    const int* __restrict__ tidsp, int thead)
{
  __shared__ __align__(16) char smem[33792];
  _Float16* As = (_Float16*)smem;              // [128][64] halfwords, swizzled
  _Float16* Ws = (_Float16*)(smem + 16384);
  const int tid = threadIdx.x;
  const int lane = tid & 63, wid = tid >> 6;
  const int wr = wid >> 1, wc = wid & 1;
  const long m0 = (long)blockIdx.y * 128;
  const int n0 = blockIdx.x * 128;

  uint4 areg[4], breg[4];

  auto loadA = [&](int k0) {
#pragma unroll
    for (int p = 0; p < 4; ++p) {
      int id = p * 256 + tid;
      int row = id >> 3, kc = id & 7;
      areg[p] = *(const uint4*)(A + (m0 + row) * (long)lda + k0 + kc * 8);
    }
  };
  auto loadB = [&](int k0) {
#pragma unroll
    for (int p = 0; p < 4; ++p) {
      int id = p * 256 + tid;
      int row = id >> 3, kc = id & 7;
      int n = n0 + row;
      uint4 z; z.x = z.y = z.z = z.w = 0u;
      breg[p] = (n < N) ? *(const uint4*)(W + (long)n * K + k0 + kc * 8) : z;
    }
  };
  auto stage = [&]() {
#pragma unroll
    for (int p = 0; p < 4; ++p) {
      int id = p * 256 + tid;
      int row = id >> 3, kc = id & 7;
      int sc = ((kc ^ (row & 7)) << 3);
      *(uint4*)&As[row * 64 + sc] = areg[p];
      *(uint4*)&Ws[row * 64 + sc] = breg[p];
    }
  };

  f32x4 acc[4][4] = {};
  loadA(0); loadB(0);
  const int la = lane & 15, lg = lane >> 4;

  for (int k0 = 0;;) {
    __syncthreads();
    stage();
    __syncthreads();
    int kn = k0 + 64;
    if (kn < K) { loadA(kn); loadB(kn); }
#pragma unroll
    for (int ks = 0; ks < 2; ++ks) {
      const int cc = ks * 4 + lg;
      f16x8 af[4], bfr[4];
#pragma unroll
      for (int i = 0; i < 4; ++i) {
        int ra = wr * 64 + i * 16 + la;
        int rb = wc * 64 + i * 16 + la;
        af[i]  = *(const f16x8*)&As[ra * 64 + ((cc ^ (ra & 7)) << 3)];
        bfr[i] = *(const f16x8*)&Ws[rb * 64 + ((cc ^ (rb & 7)) << 3)];
      }
#pragma unroll
      for (int i = 0; i < 4; ++i)
#pragma unroll
        for (int j = 0; j < 4; ++j)
          acc[i][j] = __builtin_amdgcn_mfma_f32_16x16x32_f16(af[i], bfr[j], acc[i][j], 0, 0, 0);
    }
    k0 = kn;
    if (k0 >= K) break;
  }

  // ---- coalesced epilogue via LDS transpose (2 phases of 64 rows) ----
  float* epi = (float*)smem;                    // [64][132]
  const int lr_s = tid >> 2;                    // 0..63
  const int c0_s = (tid & 3) << 5;              // 0,32,64,96
#pragma unroll
  for (int ph = 0; ph < 2; ++ph) {
    __syncthreads();
    if (wr == ph) {
#pragma unroll
      for (int i = 0; i < 4; ++i)
#pragma unroll
        for (int j = 0; j < 4; ++j)
#pragma unroll
          for (int r = 0; r < 4; ++r)
            epi[(i * 16 + lg * 4 + r) * 132 + wc * 64 + j * 16 + la] = acc[i][j][r];
    }
    __syncthreads();
    const long gr = m0 + ph * 64 + lr_s;
    if (OM == 3) {
      const int q = n0 >> 7;
      const float keep = (tidsp[gr] == thead) ? 1.f : 0.f;
      float* crow = (float*)Cv + (long)q * extra + gr * 128;
#pragma unroll
      for (int u = 0; u < 8; ++u) {
        int c = c0_s + u * 4;
        float4 v = *(float4*)&epi[lr_s * 132 + c];
        float o[4] = {v.x, v.y, v.z, v.w};
#pragma unroll
        for (int e = 0; e < 4; ++e) {
          float vv = o[e] + bias[n0 + c + e];
          if (q != 0) vv = 1.f / (1.f + expf(-vv));
          o[e] = vv * keep;
        }
        *(float4*)&crow[c] = make_float4(o[0], o[1], o[2], o[3]);
      }
    } else {
      _Float16* crow = (_Float16*)Cv + gr * ldc;
#pragma unroll
      for (int u = 0; u < 8; ++u) {
        int c = c0_s + u * 4;
        int col = n0 + c;
        if (col < N) {
          float4 v = *(float4*)&epi[lr_s * 132 + c];
          float b0 = 0.f, b1 = 0.f, b2 = 0.f, b3 = 0.f;
          if (OM == 2) { b0 = bias[col]; b1 = bias[col + 1]; b2 = bias[col + 2]; b3 = bias[col + 3]; }
          f16x4 o = {(_Float16)(v.x + b0), (_Float16)(v.y + b1),
                     (_Float16)(v.z + b2), (_Float16)(v.w + b3)};
          *(f16x4*)&crow[col] = o;
        }
      }
    }
  }
}

// ---------------------------------------------------------------------------
__global__ __launch_bounds__(256) void cvt_kernel(
    const float* __restrict__ src, _Float16* __restrict__ dst, long n4)
{
  long i = (long)blockIdx.x * 256 + threadIdx.x;
  long stride = (long)gridDim.x * 256;
  for (; i < n4; i += stride) {
    float4 v = *(const float4*)(src + i * 4);
    f16x4 o = { (_Float16)v.x, (_Float16)v.y, (_Float16)v.z, (_Float16)v.w };
    *(f16x4*)(dst + i * 4) = o;
  }
}

// how [2][4][128][768] -> packed [2][512][768] in output order; hob likewise.
__global__ __launch_bounds__(256) void pack_head_kernel(
    const float* __restrict__ how, const float* __restrict__ hob,
    _Float16* __restrict__ howb, float* __restrict__ hobp)
{
  const int wmap[4] = {0, 3, 1, 2};
  int idx = blockIdx.x * 256 + threadIdx.x;
  if (idx < 2 * 512 * 768) {
    int t = idx / (512 * 768);
    int rem = idx - t * 512 * 768;
    int q = rem / (128 * 768);
    int rem2 = rem - q * 128 * 768;
    howb[idx] = (_Float16)how[((size_t)(t * 4 + wmap[q])) * 128 * 768 + rem2];
  }
  if (idx < 1024) {
    int t = idx >> 9, rem = idx & 511;
    int q = rem >> 7, pp = rem & 127;
    hobp[idx] = hob[(t * 4 + wmap[q]) * 128 + pp];
  }
}

// ---------------------------------------------------------------------------
__global__ __launch_bounds__(256) void dt_kernel(
    const _Float16* __restrict__ zx, const float* __restrict__ dtb,
    const float* __restrict__ alog, float* __restrict__ dtp,
    float* __restrict__ dap, int total)
{
  int idx = blockIdx.x * 256 + threadIdx.x;
  if (idx >= total) return;
  int bl = idx / NHEADS, hh = idx - bl * NHEADS;
  float raw = (float)zx[(size_t)bl * D_IPROJ + (D_INNER + CONVD) + hh] + dtb[hh];
  float sp = (raw > 20.f) ? raw : log1pf(expf(raw));
  dtp[idx] = sp;
  dap[idx] = expf(-expf(alog[hh]) * sp);
}

__global__ __launch_bounds__(256) void conv_kernel(
    const _Float16* __restrict__ zx, const float* __restrict__ cw,
    const float* __restrict__ cb, float* __restrict__ xbc)
{
  int idx = blockIdx.x * 256 + threadIdx.x;
  int bl = idx / CONVD;
  int c = idx - bl * CONVD;
  int l = bl & (L_SEQ - 1);
  float acc = cb[c];
#pragma unroll
  for (int k = 0; k < 4; ++k) {
    int ls = l - 3 + k;
    if (ls >= 0)
      acc = fmaf(cw[c * 4 + k],
                 (float)zx[(size_t)(bl - 3 + k) * D_IPROJ + D_INNER + c], acc);
  }
  xbc[(size_t)bl * CONVD + c] = acc / (1.f + expf(-acc));
}

// ---------------------------------------------------------------------------
// Scan pass A: per (b,h,seg) local scan (h0=0). x read / y written directly
// (prefetched); B/C staged in LDS; cumq via wave prefix product.
// ---------------------------------------------------------------------------
__global__ __launch_bounds__(64) void scanA_kernel(
    float* __restrict__ xbc, const float* __restrict__ dtp,
    const float* __restrict__ dap, const float* __restrict__ Dv,
    float* __restrict__ Hseg, float* __restrict__ cumq)
{
  __shared__ float sbc[SEGLEN][32];
  __shared__ float sdt[SEGLEN], sda[SEGLEN];
  const int lane = threadIdx.x;
  const int seg = blockIdx.x & (NSEG - 1);
  const int bh = blockIdx.x >> 6;
  const int h = bh % NHEADS, b = bh / NHEADS;
  const float Dh = Dv[h];
  const int bl0 = b * L_SEQ + seg * SEGLEN;

  for (int i = lane; i < SEGLEN * 8; i += 64) {
    int t = i >> 3, q = (i & 7) << 2;
    *(float4*)&sbc[t][q] = *(const float4*)&xbc[(size_t)(bl0 + t) * CONVD + D_INNER + q];
  }
  sdt[lane] = dtp[(size_t)(bl0 + lane) * NHEADS + h];
  float myda = dap[(size_t)(bl0 + lane) * NHEADS + h];
  sda[lane] = myda;
  __syncthreads();

  // inclusive prefix product of dA across the 64 lanes (= 64 timesteps)
  float pp = myda;
#pragma unroll
  for (int off = 1; off < 64; off <<= 1) {
    float tv = __shfl_up(pp, off, 64);
    if (lane >= off) pp *= tv;
  }
  cumq[(size_t)bh * L_SEQ + seg * SEGLEN + lane] = pp;

  float hs[16];
#pragma unroll
  for (int n = 0; n < 16; ++n) hs[n] = 0.f;

  size_t xaddr = (size_t)bl0 * CONVD + h * HEADDIM + lane;
  float xv = xbc[xaddr];
  for (int t = 0; t < SEGLEN; ++t) {
    float xn = (t < SEGLEN - 1) ? xbc[xaddr + CONVD] : 0.f;
    float dav = sda[t];
    float coef = sdt[t] * xv;
    float y0 = 0.f, y1 = 0.f, y2 = 0.f, y3 = 0.f;
#pragma unroll
    for (int n = 0; n < 16; ++n) {
      float hv = fmaf(hs[n], dav, coef * sbc[t][n]);
      hs[n] = hv;
      float cvv = sbc[t][16 + n];
      if ((n & 3) == 0)      y0 = fmaf(hv, cvv, y0);
      else if ((n & 3) == 1) y1 = fmaf(hv, cvv, y1);
      else if ((n & 3) == 2) y2 = fmaf(hv, cvv, y2);
      else                   y3 = fmaf(hv, cvv, y3);
    }
    xbc[xaddr] = fmaf(Dh, xv, (y0 + y1) + (y2 + y3));
    xv = xn;
    xaddr += CONVD;
  }

  float* Hst = Hseg + ((size_t)bh * NSEG + seg) * 1024 + lane * 16;
#pragma unroll
  for (int n = 0; n < 16; n += 4)
    *(float4*)&Hst[n] = make_float4(hs[n], hs[n + 1], hs[n + 2], hs[n + 3]);
}

// Pass B: per (b,h) combine across segments; Hseg slot becomes ENTRY state.
__global__ __launch_bounds__(64) void scanB_kernel(
    float* __restrict__ Hseg, const float* __restrict__ cumq)
{
  const int lane = threadIdx.x;
  const int bh = blockIdx.x;
  float hin[16];
#pragma unroll
  for (int n = 0; n < 16; ++n) hin[n] = 0.f;
  for (int s = 0; s < NSEG; ++s) {
    float* slot = Hseg + ((size_t)bh * NSEG + s) * 1024 + lane * 16;
    float P = cumq[(size_t)bh * L_SEQ + s * SEGLEN + (SEGLEN - 1)];
    float hl[16];
#pragma unroll
    for (int n = 0; n < 16; n += 4) {
      float4 v = *(float4*)(slot + n);
      hl[n] = v.x; hl[n + 1] = v.y; hl[n + 2] = v.z; hl[n + 3] = v.w;
    }
#pragma unroll
    for (int n = 0; n < 16; n += 4)
      *(float4*)(slot + n) = make_float4(hin[n], hin[n + 1], hin[n + 2], hin[n + 3]);
#pragma unroll
    for (int n = 0; n < 16; ++n) hin[n] = fmaf(P, hin[n], hl[n]);
  }
}

// Pass C: y += cumprod * (C . h_entry)
__global__ __launch_bounds__(64) void scanC_kernel(
    float* __restrict__ xbc, const float* __restrict__ Hseg,
    const float* __restrict__ cumq)
{
  const int seg = blockIdx.x & (NSEG - 1);
  if (seg == 0) return;   // entry state is exactly zero
  __shared__ float sc[SEGLEN][16];
  __shared__ float scq[SEGLEN];
  const int lane = threadIdx.x;
  const int bh = blockIdx.x >> 6;
  const int h = bh % NHEADS, b = bh / NHEADS;
  const int bl0 = b * L_SEQ + seg * SEGLEN;
  const float* slot = Hseg + ((size_t)bh * NSEG + seg) * 1024 + lane * 16;
  float hin[16];
#pragma unroll
  for (int n = 0; n < 16; n += 4) {
    float4 v = *(const float4*)(slot + n);
    hin[n] = v.x; hin[n + 1] = v.y; hin[n + 2] = v.z; hin[n + 3] = v.w;
  }
  for (int i = lane; i < SEGLEN * 4; i += 64) {
    int t = i >> 2, q = (i & 3) << 2;
    *(float4*)&sc[t][q] =
        *(const float4*)&xbc[(size_t)(bl0 + t) * CONVD + D_INNER + D_STATE + q];
  }
  scq[lane] = cumq[(size_t)bh * L_SEQ + seg * SEGLEN + lane];
  __syncthreads();
  for (int t = 0; t < SEGLEN; ++t) {
    float dot = 0.f;
#pragma unroll
    for (int n = 0; n < 16; ++n) dot = fmaf(hin[n], sc[t][n], dot);
    size_t ad = (size_t)(bl0 + t) * CONVD + h * HEADDIM + lane;
    xbc[ad] = fmaf(scq[t], dot, xbc[ad]);
  }
}

// ---------------------------------------------------------------------------
// y *= silu(z); RMS-norm over 1536; * norm_w; f16 out overlaid on zx cols 0..
// ---------------------------------------------------------------------------
__global__ __launch_bounds__(256) void norm_kernel(
    const float* __restrict__ y, const _Float16* __restrict__ zx,
    const float* __restrict__ nw, _Float16* __restrict__ ybf)
{
  const int row = blockIdx.x;
  const int tid = threadIdx.x;
  const float* yr = y + (size_t)row * CONVD;
  const _Float16* zr = zx + (size_t)row * D_IPROJ;
  float v[6];
  float ss = 0.f;
#pragma unroll
  for (int jj = 0; jj < 6; ++jj) {
    int c = jj * 256 + tid;
    float yv = yr[c];
    float zv = (float)zr[c];
    float sz = zv / (1.f + expf(-zv));
    float val = yv * sz;
    v[jj] = val;
    ss = fmaf(val, val, ss);
  }
#pragma unroll
  for (int off = 32; off > 0; off >>= 1) ss += __shfl_xor(ss, off, 64);
  __shared__ float red[4];
  if ((tid & 63) == 0) red[tid >> 6] = ss;
  __syncthreads();
  float tot = red[0] + red[1] + red[2] + red[3];
  float rs = rsqrtf(tot * (1.f / 1536.f) + 1e-5f);
  _Float16* orow = ybf + (size_t)row * D_IPROJ;
#pragma unroll
  for (int jj = 0; jj < 6; ++jj) {
    int c = jj * 256 + tid;
    orow[c] = (_Float16)(v[jj] * rs * nw[c]);
  }
}

// ---------------------------------------------------------------------------
extern "C" void kernel_launch(void* const* d_in, const int* in_sizes, int n_in,
                              void* d_out, int out_size, void* d_ws, size_t ws_size,
                              hipStream_t stream)
{
  const float* x_in = (const float*)d_in[0];
  const int*   tids = (const int*)d_in[1];
  const float* ipw  = (const float*)d_in[2];
  const float* cw   = (const float*)d_in[3];
  const float* cb   = (const float*)d_in[4];
  const float* dtb  = (const float*)d_in[5];
  const float* alog = (const float*)d_in[6];
  const float* Dv   = (const float*)d_in[7];
  const float* nw   = (const float*)d_in[8];
  const float* opw  = (const float*)d_in[9];
  const float* hw   = (const float*)d_in[10];
  const float* hb   = (const float*)d_in[11];
  const float* how  = (const float*)d_in[12];
  const float* hob  = (const float*)d_in[13];
  float* out = (float*)d_out;

  // ---- workspace carve: f16 weights + per-chunk activations ----
  char* p = (char*)d_ws;
  _Float16* ipw_b = (_Float16*)p; p += (size_t)14413824 * 2;  // 6*3128*768
  _Float16* opw_b = (_Float16*)p; p += (size_t)7077888 * 2;   // 6*768*1536
  _Float16* hw_b  = (_Float16*)p; p += (size_t)1179648 * 2;   // 2*768*768
  _Float16* how_b = (_Float16*)p; p += (size_t)786432 * 2;    // 2*512*768
  float*    hob_p = (float*)p;    p += (size_t)1024 * 4;
  const size_t used_w = (size_t)(p - (char*)d_ws);
  // per batch: zx f16 25.66MB + xbc 25.69MB + Hseg 6.29MB + dt/da/cumq 1.18MB + xbuf 6.29MB
  const size_t PB = 65077248;
  int nb = 4;
  while (nb > 1 && used_w + (size_t)nb * PB > ws_size) nb >>= 1;

  // ---- weight conversions (idempotent, every launch) ----
  cvt_kernel<<<8192, 256, 0, stream>>>(ipw, ipw_b, 14413824 / 4);
  cvt_kernel<<<6912, 256, 0, stream>>>(opw, opw_b, 7077888 / 4);
  cvt_kernel<<<1152, 256, 0, stream>>>(hw, hw_b, 1179648 / 4);
  pack_head_kernel<<<3072, 256, 0, stream>>>(how, hob, how_b, hob_p);

  for (int b0 = 0; b0 < BATCH; b0 += nb) {
    const int MT = nb * L_SEQ;
    _Float16* zx  = (_Float16*)p;
    float* xbc  = (float*)(zx + (size_t)MT * D_IPROJ);
    float* Hseg = xbc + (size_t)MT * CONVD;
    float* dtp  = Hseg + (size_t)nb * NHEADS * NSEG * 1024;
    float* dap  = dtp + (size_t)MT * NHEADS;
    float* cumq = dap + (size_t)MT * NHEADS;
    _Float16* xbuf = (_Float16*)(cumq + (size_t)MT * NHEADS);
    _Float16* ybf  = zx;   // overlay: norm output, stride D_IPROJ
    _Float16* Hbf  = zx;   // overlay: head hidden, stride D_IPROJ

    cvt_kernel<<<6144, 256, 0, stream>>>(x_in + (size_t)b0 * L_SEQ * DIMM,
                                         xbuf, (long)MT * DIMM / 4);

    for (int i = 0; i < 6; ++i) {
      gemm_mfma<0><<<dim3((D_IPROJ + 127) / 128, MT / 128), 256, 0, stream>>>(
          xbuf, DIMM, ipw_b + (size_t)i * D_IPROJ * DIMM, nullptr,
          zx, D_IPROJ, 0, MT, D_IPROJ, DIMM, nullptr, 0);
      dt_kernel<<<(MT * NHEADS + 255) / 256, 256, 0, stream>>>(
          zx, dtb + i * NHEADS, alog + i * NHEADS, dtp, dap, MT * NHEADS);
      conv_kernel<<<(MT * CONVD) / 256, 256, 0, stream>>>(
          zx, cw + (size_t)i * CONVD * 4, cb + i * CONVD, xbc);
      scanA_kernel<<<nb * NHEADS * NSEG, 64, 0, stream>>>(
          xbc, dtp, dap, Dv + i * NHEADS, Hseg, cumq);
      scanB_kernel<<<nb * NHEADS, 64, 0, stream>>>(Hseg, cumq);
      scanC_kernel<<<nb * NHEADS * NSEG, 64, 0, stream>>>(xbc, Hseg, cumq);
      norm_kernel<<<MT, 256, 0, stream>>>(xbc, zx, nw + i * D_INNER, ybf);
      gemm_mfma<0><<<dim3(DIMM / 128, MT / 128), 256, 0, stream>>>(
          ybf, D_IPROJ, opw_b + (size_t)i * DIMM * D_INNER, nullptr,
          xbuf, DIMM, 0, MT, DIMM, D_INNER, nullptr, 0);
    }

    for (int t = 0; t < 2; ++t) {
      gemm_mfma<2><<<dim3(DIMM / 128, MT / 128), 256, 0, stream>>>(
          xbuf, DIMM, hw_b + (size_t)t * DIMM * DIMM, hb + t * DIMM,
          Hbf, D_IPROJ, 0, MT, DIMM, DIMM, nullptr, 0);
      gemm_mfma<3><<<dim3(4, MT / 128), 256, 0, stream>>>(
          Hbf, D_IPROJ, how_b + (size_t)t * 512 * DIMM, hob_p + t * 512,
          out + (size_t)t * 4 * 16384 * 128 + (size_t)b0 * L_SEQ * 128,
          128, (long)16384 * 128, MT, 512, DIMM,
          tids + (size_t)b0 * L_SEQ, t);
    }
  }
}

// Round 6
// 7637.999 us; speedup vs baseline: 3.6664x; 1.0383x over previous
//
#include <hip/hip_runtime.h>
#include <cstdint>
#include <cstddef>

#define L_SEQ   4096
#define BATCH   4
#define DIMM    768
#define D_INNER 1536
#define NHEADS  24
#define HEADDIM 64
#define D_STATE 16
#define CONVD   1568
#define D_IPROJ 3128
#define NPITCH  128
#define SEGLEN  64
#define NSEG    (L_SEQ / SEGLEN)   // 64

typedef _Float16 f16x8 __attribute__((ext_vector_type(8)));
typedef _Float16 f16x4 __attribute__((ext_vector_type(4)));
typedef float    f32x4 __attribute__((ext_vector_type(4)));

// ---------------------------------------------------------------------------
// f16 MFMA GEMM: C[m,n] = sum_k A[m*lda+k]*W[n*K+k] (+bias). 128x128x64 tile,
// 4 waves (2x2), 16x16x32 MFMA, XOR-swizzled LDS.
// Block mapping: XCD-band swizzle (xcd = flat%8 owns row band, sweeps cols
// with W-tile hot in its L2). Requires (M/128) % 8 == 0 (M mult of 1024).
// Epilogue: LDS transpose, then FULL-LINE stores (consecutive lanes write
// consecutive 16B; each 64B line filled by 4 lanes in ONE instruction).
// OM: 0 = f16 out (+ col<N guard), 2 = f16 out + f32 bias,
//     3 = f32 out + bias + sigmoid(q>0) + type-mask (head fusion; N=512)
// ---------------------------------------------------------------------------
template <int OM>
__global__ __launch_bounds__(256, 2) void gemm_mfma(
    const _Float16* __restrict__ A, int lda,
    const _Float16* __restrict__ W,
    const float* __restrict__ bias,
    void* __restrict__ Cv, long ldc, long extra,
    int M, int N, int K,
    const int* __restrict__ tidsp, int thead)
{
  __shared__ __align__(16) char smem[33792];
  _Float16* As = (_Float16*)smem;              // [128][64] halfwords, swizzled
  _Float16* Ws = (_Float16*)(smem + 16384);
  const int tid = threadIdx.x;
  const int lane = tid & 63, wid = tid >> 6;
  const int wr = wid >> 1, wc = wid & 1;

  // ---- XCD-band block swizzle ----
  const int nbx = gridDim.x, nby = gridDim.y;
  const int flat = blockIdx.y * nbx + blockIdx.x;
  const int xcd = flat & 7;
  const int idx = flat >> 3;
  const int rpx = nby >> 3;             // row-tiles per XCD (4 or 8)
  const int rl = idx % rpx;
  const int ct = idx / rpx;
  const long m0 = (long)(xcd * rpx + rl) * 128;
  const int n0 = ct * 128;

  uint4 areg[4], breg[4];

  auto loadA = [&](int k0) {
#pragma unroll
    for (int p = 0; p < 4; ++p) {
      int id = p * 256 + tid;
      int row = id >> 3, kc = id & 7;
      areg[p] = *(const uint4*)(A + (m0 + row) * (long)lda + k0 + kc * 8);
    }
  };
  auto loadB = [&](int k0) {
#pragma unroll
    for (int p = 0; p < 4; ++p) {
      int id = p * 256 + tid;
      int row = id >> 3, kc = id & 7;
      int n = n0 + row;
      uint4 z; z.x = z.y = z.z = z.w = 0u;
      breg[p] = (n < N) ? *(const uint4*)(W + (long)n * K + k0 + kc * 8) : z;
    }
  };
  auto stage = [&]() {
#pragma unroll
    for (int p = 0; p < 4; ++p) {
      int id = p * 256 + tid;
      int row = id >> 3, kc = id & 7;
      int sc = ((kc ^ (row & 7)) << 3);
      *(uint4*)&As[row * 64 + sc] = areg[p];
      *(uint4*)&Ws[row * 64 + sc] = breg[p];
    }
  };

  f32x4 acc[4][4] = {};
  loadA(0); loadB(0);
  const int la = lane & 15, lg = lane >> 4;

  for (int k0 = 0;;) {
    __syncthreads();
    stage();
    __syncthreads();
    int kn = k0 + 64;
    if (kn < K) { loadA(kn); loadB(kn); }
#pragma unroll
    for (int ks = 0; ks < 2; ++ks) {
      const int cc = ks * 4 + lg;
      f16x8 af[4], bfr[4];
#pragma unroll
      for (int i = 0; i < 4; ++i) {
        int ra = wr * 64 + i * 16 + la;
        int rb = wc * 64 + i * 16 + la;
        af[i]  = *(const f16x8*)&As[ra * 64 + ((cc ^ (ra & 7)) << 3)];
        bfr[i] = *(const f16x8*)&Ws[rb * 64 + ((cc ^ (rb & 7)) << 3)];
      }
#pragma unroll
      for (int i = 0; i < 4; ++i)
#pragma unroll
        for (int j = 0; j < 4; ++j)
          acc[i][j] = __builtin_amdgcn_mfma_f32_16x16x32_f16(af[i], bfr[j], acc[i][j], 0, 0, 0);
    }
    k0 = kn;
    if (k0 >= K) break;
  }

  // ---- epilogue via LDS transpose (2 phases of 64 rows) ----
  float* epi = (float*)smem;                    // [64][132]
#pragma unroll
  for (int ph = 0; ph < 2; ++ph) {
    __syncthreads();
    if (wr == ph) {
#pragma unroll
      for (int i = 0; i < 4; ++i)
#pragma unroll
        for (int j = 0; j < 4; ++j)
#pragma unroll
          for (int r = 0; r < 4; ++r)
            epi[(i * 16 + lg * 4 + r) * 132 + wc * 64 + j * 16 + la] = acc[i][j][r];
    }
    __syncthreads();
    if (OM == 3) {
      // f32 out: 128 cols = 512B/row; 8 passes x 8 rows; 32 lanes cover a row
      const int q = n0 >> 7;
      const int rr = tid >> 5;        // 0..7
      const int ch = tid & 31;        // 16B chunk within row
#pragma unroll
      for (int ps = 0; ps < 8; ++ps) {
        int lrow = ps * 8 + rr;
        long gr = m0 + ph * 64 + lrow;
        float keep = (tidsp[gr] == thead) ? 1.f : 0.f;
        float4 v = *(float4*)&epi[lrow * 132 + ch * 4];
        float o[4] = {v.x, v.y, v.z, v.w};
#pragma unroll
        for (int e = 0; e < 4; ++e) {
          float vv = o[e] + bias[n0 + ch * 4 + e];
          if (q != 0) vv = 1.f / (1.f + expf(-vv));
          o[e] = vv * keep;
        }
        *(float4*)((float*)Cv + (long)q * extra + gr * 128 + ch * 4) =
            make_float4(o[0], o[1], o[2], o[3]);
      }
    } else {
      // f16 out: 16 passesx... 4 passes x 16 rows; 16 lanes cover 256B row
      const int rr = tid >> 4;        // 0..15
      const int ch = tid & 15;        // 16B (8-f16) chunk
      const int col = n0 + ch * 8;
      float b[8] = {0.f, 0.f, 0.f, 0.f, 0.f, 0.f, 0.f, 0.f};
      if (OM == 2 && col < N) {
#pragma unroll
        for (int e = 0; e < 8; ++e) b[e] = bias[col + e];
      }
#pragma unroll
      for (int ps = 0; ps < 4; ++ps) {
        int lrow = ps * 16 + rr;
        long gr = m0 + ph * 64 + lrow;
        if (col < N) {
          float4 v0 = *(float4*)&epi[lrow * 132 + ch * 8];
          float4 v1 = *(float4*)&epi[lrow * 132 + ch * 8 + 4];
          f16x8 o = {(_Float16)(v0.x + b[0]), (_Float16)(v0.y + b[1]),
                     (_Float16)(v0.z + b[2]), (_Float16)(v0.w + b[3]),
                     (_Float16)(v1.x + b[4]), (_Float16)(v1.y + b[5]),
                     (_Float16)(v1.z + b[6]), (_Float16)(v1.w + b[7])};
          *(f16x8*)((_Float16*)Cv + gr * ldc + col) = o;
        }
      }
    }
  }
}

// ---------------------------------------------------------------------------
__global__ __launch_bounds__(256) void cvt_kernel(
    const float* __restrict__ src, _Float16* __restrict__ dst, long n4)
{
  long i = (long)blockIdx.x * 256 + threadIdx.x;
  long stride = (long)gridDim.x * 256;
  for (; i < n4; i += stride) {
    float4 v = *(const float4*)(src + i * 4);
    f16x4 o = { (_Float16)v.x, (_Float16)v.y, (_Float16)v.z, (_Float16)v.w };
    *(f16x4*)(dst + i * 4) = o;
  }
}

// how [2][4][128][768] -> packed [2][512][768] in output order; hob likewise.
__global__ __launch_bounds__(256) void pack_head_kernel(
    const float* __restrict__ how, const float* __restrict__ hob,
    _Float16* __restrict__ howb, float* __restrict__ hobp)
{
  const int wmap[4] = {0, 3, 1, 2};
  int idx = blockIdx.x * 256 + threadIdx.x;
  if (idx < 2 * 512 * 768) {
    int t = idx / (512 * 768);
    int rem = idx - t * 512 * 768;
    int q = rem / (128 * 768);
    int rem2 = rem - q * 128 * 768;
    howb[idx] = (_Float16)how[((size_t)(t * 4 + wmap[q])) * 128 * 768 + rem2];
  }
  if (idx < 1024) {
    int t = idx >> 9, rem = idx & 511;
    int q = rem >> 7, pp = rem & 127;
    hobp[idx] = hob[(t * 4 + wmap[q]) * 128 + pp];
  }
}

// ---------------------------------------------------------------------------
__global__ __launch_bounds__(256) void dt_kernel(
    const _Float16* __restrict__ zx, const float* __restrict__ dtb,
    const float* __restrict__ alog, float* __restrict__ dtp,
    float* __restrict__ dap, int total)
{
  int idx = blockIdx.x * 256 + threadIdx.x;
  if (idx >= total) return;
  int bl = idx / NHEADS, hh = idx - bl * NHEADS;
  float raw = (float)zx[(size_t)bl * D_IPROJ + (D_INNER + CONVD) + hh] + dtb[hh];
  float sp = (raw > 20.f) ? raw : log1pf(expf(raw));
  dtp[idx] = sp;
  dap[idx] = expf(-expf(alog[hh]) * sp);
}

__global__ __launch_bounds__(256) void conv_kernel(
    const _Float16* __restrict__ zx, const float* __restrict__ cw,
    const float* __restrict__ cb, float* __restrict__ xbc)
{
  int idx = blockIdx.x * 256 + threadIdx.x;
  int bl = idx / CONVD;
  int c = idx - bl * CONVD;
  int l = bl & (L_SEQ - 1);
  float acc = cb[c];
#pragma unroll
  for (int k = 0; k < 4; ++k) {
    int ls = l - 3 + k;
    if (ls >= 0)
      acc = fmaf(cw[c * 4 + k],
                 (float)zx[(size_t)(bl - 3 + k) * D_IPROJ + D_INNER + c], acc);
  }
  xbc[(size_t)bl * CONVD + c] = acc / (1.f + expf(-acc));
}

// ---------------------------------------------------------------------------
// Scan pass A: per (b,h,seg) local scan (h0=0). x read / y written directly
// (prefetched); B/C staged in LDS; cumq via wave prefix product.
// ---------------------------------------------------------------------------
__global__ __launch_bounds__(64) void scanA_kernel(
    float* __restrict__ xbc, const float* __restrict__ dtp,
    const float* __restrict__ dap, const float* __restrict__ Dv,
    float* __restrict__ Hseg, float* __restrict__ cumq)
{
  __shared__ float sbc[SEGLEN][32];
  __shared__ float sdt[SEGLEN], sda[SEGLEN];
  const int lane = threadIdx.x;
  const int seg = blockIdx.x & (NSEG - 1);
  const int bh = blockIdx.x >> 6;
  const int h = bh % NHEADS, b = bh / NHEADS;
  const float Dh = Dv[h];
  const int bl0 = b * L_SEQ + seg * SEGLEN;

  for (int i = lane; i < SEGLEN * 8; i += 64) {
    int t = i >> 3, q = (i & 7) << 2;
    *(float4*)&sbc[t][q] = *(const float4*)&xbc[(size_t)(bl0 + t) * CONVD + D_INNER + q];
  }
  sdt[lane] = dtp[(size_t)(bl0 + lane) * NHEADS + h];
  float myda = dap[(size_t)(bl0 + lane) * NHEADS + h];
  sda[lane] = myda;
  __syncthreads();

  // inclusive prefix product of dA across the 64 lanes (= 64 timesteps)
  float pp = myda;
#pragma unroll
  for (int off = 1; off < 64; off <<= 1) {
    float tv = __shfl_up(pp, off, 64);
    if (lane >= off) pp *= tv;
  }
  cumq[(size_t)bh * L_SEQ + seg * SEGLEN + lane] = pp;

  float hs[16];
#pragma unroll
  for (int n = 0; n < 16; ++n) hs[n] = 0.f;

  size_t xaddr = (size_t)bl0 * CONVD + h * HEADDIM + lane;
  float xv = xbc[xaddr];
  for (int t = 0; t < SEGLEN; ++t) {
    float xn = (t < SEGLEN - 1) ? xbc[xaddr + CONVD] : 0.f;
    float dav = sda[t];
    float coef = sdt[t] * xv;
    float y0 = 0.f, y1 = 0.f, y2 = 0.f, y3 = 0.f;
#pragma unroll
    for (int n = 0; n < 16; ++n) {
      float hv = fmaf(hs[n], dav, coef * sbc[t][n]);
      hs[n] = hv;
      float cvv = sbc[t][16 + n];
      if ((n & 3) == 0)      y0 = fmaf(hv, cvv, y0);
      else if ((n & 3) == 1) y1 = fmaf(hv, cvv, y1);
      else if ((n & 3) == 2) y2 = fmaf(hv, cvv, y2);
      else                   y3 = fmaf(hv, cvv, y3);
    }
    xbc[xaddr] = fmaf(Dh, xv, (y0 + y1) + (y2 + y3));
    xv = xn;
    xaddr += CONVD;
  }

  float* Hst = Hseg + ((size_t)bh * NSEG + seg) * 1024 + lane * 16;
#pragma unroll
  for (int n = 0; n < 16; n += 4)
    *(float4*)&Hst[n] = make_float4(hs[n], hs[n + 1], hs[n + 2], hs[n + 3]);
}

// Pass B: per (b,h) combine across segments; Hseg slot becomes ENTRY state.
__global__ __launch_bounds__(64) void scanB_kernel(
    float* __restrict__ Hseg, const float* __restrict__ cumq)
{
  const int lane = threadIdx.x;
  const int bh = blockIdx.x;
  float hin[16];
#pragma unroll
  for (int n = 0; n < 16; ++n) hin[n] = 0.f;
  for (int s = 0; s < NSEG; ++s) {
    float* slot = Hseg + ((size_t)bh * NSEG + s) * 1024 + lane * 16;
    float P = cumq[(size_t)bh * L_SEQ + s * SEGLEN + (SEGLEN - 1)];
    float hl[16];
#pragma unroll
    for (int n = 0; n < 16; n += 4) {
      float4 v = *(float4*)(slot + n);
      hl[n] = v.x; hl[n + 1] = v.y; hl[n + 2] = v.z; hl[n + 3] = v.w;
    }
#pragma unroll
    for (int n = 0; n < 16; n += 4)
      *(float4*)(slot + n) = make_float4(hin[n], hin[n + 1], hin[n + 2], hin[n + 3]);
#pragma unroll
    for (int n = 0; n < 16; ++n) hin[n] = fmaf(P, hin[n], hl[n]);
  }
}

// Pass C: y += cumprod * (C . h_entry)
__global__ __launch_bounds__(64) void scanC_kernel(
    float* __restrict__ xbc, const float* __restrict__ Hseg,
    const float* __restrict__ cumq)
{
  const int seg = blockIdx.x & (NSEG - 1);
  if (seg == 0) return;   // entry state is exactly zero
  __shared__ float sc[SEGLEN][16];
  __shared__ float scq[SEGLEN];
  const int lane = threadIdx.x;
  const int bh = blockIdx.x >> 6;
  const int h = bh % NHEADS, b = bh / NHEADS;
  const int bl0 = b * L_SEQ + seg * SEGLEN;
  const float* slot = Hseg + ((size_t)bh * NSEG + seg) * 1024 + lane * 16;
  float hin[16];
#pragma unroll
  for (int n = 0; n < 16; n += 4) {
    float4 v = *(const float4*)(slot + n);
    hin[n] = v.x; hin[n + 1] = v.y; hin[n + 2] = v.z; hin[n + 3] = v.w;
  }
  for (int i = lane; i < SEGLEN * 4; i += 64) {
    int t = i >> 2, q = (i & 3) << 2;
    *(float4*)&sc[t][q] =
        *(const float4*)&xbc[(size_t)(bl0 + t) * CONVD + D_INNER + D_STATE + q];
  }
  scq[lane] = cumq[(size_t)bh * L_SEQ + seg * SEGLEN + lane];
  __syncthreads();
  for (int t = 0; t < SEGLEN; ++t) {
    float dot = 0.f;
#pragma unroll
    for (int n = 0; n < 16; ++n) dot = fmaf(hin[n], sc[t][n], dot);
    size_t ad = (size_t)(bl0 + t) * CONVD + h * HEADDIM + lane;
    xbc[ad] = fmaf(scq[t], dot, xbc[ad]);
  }
}

// ---------------------------------------------------------------------------
// y *= silu(z); RMS-norm over 1536; * norm_w; f16 out overlaid on zx cols 0..
// ---------------------------------------------------------------------------
__global__ __launch_bounds__(256) void norm_kernel(
    const float* __restrict__ y, const _Float16* __restrict__ zx,
    const float* __restrict__ nw, _Float16* __restrict__ ybf)
{
  const int row = blockIdx.x;
  const int tid = threadIdx.x;
  const float* yr = y + (size_t)row * CONVD;
  const _Float16* zr = zx + (size_t)row * D_IPROJ;
  float v[6];
  float ss = 0.f;
#pragma unroll
  for (int jj = 0; jj < 6; ++jj) {
    int c = jj * 256 + tid;
    float yv = yr[c];
    float zv = (float)zr[c];
    float sz = zv / (1.f + expf(-zv));
    float val = yv * sz;
    v[jj] = val;
    ss = fmaf(val, val, ss);
  }
#pragma unroll
  for (int off = 32; off > 0; off >>= 1) ss += __shfl_xor(ss, off, 64);
  __shared__ float red[4];
  if ((tid & 63) == 0) red[tid >> 6] = ss;
  __syncthreads();
  float tot = red[0] + red[1] + red[2] + red[3];
  float rs = rsqrtf(tot * (1.f / 1536.f) + 1e-5f);
  _Float16* orow = ybf + (size_t)row * D_IPROJ;
#pragma unroll
  for (int jj = 0; jj < 6; ++jj) {
    int c = jj * 256 + tid;
    orow[c] = (_Float16)(v[jj] * rs * nw[c]);
  }
}

// ---------------------------------------------------------------------------
extern "C" void kernel_launch(void* const* d_in, const int* in_sizes, int n_in,
                              void* d_out, int out_size, void* d_ws, size_t ws_size,
                              hipStream_t stream)
{
  const float* x_in = (const float*)d_in[0];
  const int*   tids = (const int*)d_in[1];
  const float* ipw  = (const float*)d_in[2];
  const float* cw   = (const float*)d_in[3];
  const float* cb   = (const float*)d_in[4];
  const float* dtb  = (const float*)d_in[5];
  const float* alog = (const float*)d_in[6];
  const float* Dv   = (const float*)d_in[7];
  const float* nw   = (const float*)d_in[8];
  const float* opw  = (const float*)d_in[9];
  const float* hw   = (const float*)d_in[10];
  const float* hb   = (const float*)d_in[11];
  const float* how  = (const float*)d_in[12];
  const float* hob  = (const float*)d_in[13];
  float* out = (float*)d_out;

  // ---- workspace carve: f16 weights + per-chunk activations ----
  char* p = (char*)d_ws;
  _Float16* ipw_b = (_Float16*)p; p += (size_t)14413824 * 2;  // 6*3128*768
  _Float16* opw_b = (_Float16*)p; p += (size_t)7077888 * 2;   // 6*768*1536
  _Float16* hw_b  = (_Float16*)p; p += (size_t)1179648 * 2;   // 2*768*768
  _Float16* how_b = (_Float16*)p; p += (size_t)786432 * 2;    // 2*512*768
  float*    hob_p = (float*)p;    p += (size_t)1024 * 4;
  const size_t used_w = (size_t)(p - (char*)d_ws);
  // per batch: zx f16 25.66MB + xbc 25.69MB + Hseg 6.29MB + dt/da/cumq 1.18MB + xbuf 6.29MB
  const size_t PB = 65077248;
  int nb = 4;
  while (nb > 1 && used_w + (size_t)nb * PB > ws_size) nb >>= 1;

  // ---- weight conversions (idempotent, every launch) ----
  cvt_kernel<<<8192, 256, 0, stream>>>(ipw, ipw_b, 14413824 / 4);
  cvt_kernel<<<6912, 256, 0, stream>>>(opw, opw_b, 7077888 / 4);
  cvt_kernel<<<1152, 256, 0, stream>>>(hw, hw_b, 1179648 / 4);
  pack_head_kernel<<<3072, 256, 0, stream>>>(how, hob, how_b, hob_p);

  for (int b0 = 0; b0 < BATCH; b0 += nb) {
    const int MT = nb * L_SEQ;
    _Float16* zx  = (_Float16*)p;
    float* xbc  = (float*)(zx + (size_t)MT * D_IPROJ);
    float* Hseg = xbc + (size_t)MT * CONVD;
    float* dtp  = Hseg + (size_t)nb * NHEADS * NSEG * 1024;
    float* dap  = dtp + (size_t)MT * NHEADS;
    float* cumq = dap + (size_t)MT * NHEADS;
    _Float16* xbuf = (_Float16*)(cumq + (size_t)MT * NHEADS);
    _Float16* ybf  = zx;   // overlay: norm output, stride D_IPROJ
    _Float16* Hbf  = zx;   // overlay: head hidden, stride D_IPROJ

    cvt_kernel<<<6144, 256, 0, stream>>>(x_in + (size_t)b0 * L_SEQ * DIMM,
                                         xbuf, (long)MT * DIMM / 4);

    for (int i = 0; i < 6; ++i) {
      gemm_mfma<0><<<dim3((D_IPROJ + 127) / 128, MT / 128), 256, 0, stream>>>(
          xbuf, DIMM, ipw_b + (size_t)i * D_IPROJ * DIMM, nullptr,
          zx, D_IPROJ, 0, MT, D_IPROJ, DIMM, nullptr, 0);
      dt_kernel<<<(MT * NHEADS + 255) / 256, 256, 0, stream>>>(
          zx, dtb + i * NHEADS, alog + i * NHEADS, dtp, dap, MT * NHEADS);
      conv_kernel<<<(MT * CONVD) / 256, 256, 0, stream>>>(
          zx, cw + (size_t)i * CONVD * 4, cb + i * CONVD, xbc);
      scanA_kernel<<<nb * NHEADS * NSEG, 64, 0, stream>>>(
          xbc, dtp, dap, Dv + i * NHEADS, Hseg, cumq);
      scanB_kernel<<<nb * NHEADS, 64, 0, stream>>>(Hseg, cumq);
      scanC_kernel<<<nb * NHEADS * NSEG, 64, 0, stream>>>(xbc, Hseg, cumq);
      norm_kernel<<<MT, 256, 0, stream>>>(xbc, zx, nw + i * D_INNER, ybf);
      gemm_mfma<0><<<dim3(DIMM / 128, MT / 128), 256, 0, stream>>>(
          ybf, D_IPROJ, opw_b + (size_t)i * DIMM * D_INNER, nullptr,
          xbuf, DIMM, 0, MT, DIMM, D_INNER, nullptr, 0);
    }

    for (int t = 0; t < 2; ++t) {
      gemm_mfma<2><<<dim3(DIMM / 128, MT / 128), 256, 0, stream>>>(
          xbuf, DIMM, hw_b + (size_t)t * DIMM * DIMM, hb + t * DIMM,
          Hbf, D_IPROJ, 0, MT, DIMM, DIMM, nullptr, 0);
      gemm_mfma<3><<<dim3(4, MT / 128), 256, 0, stream>>>(
          Hbf, D_IPROJ, how_b + (size_t)t * 512 * DIMM, hob_p + t * 512,
          out + (size_t)t * 4 * 16384 * 128 + (size_t)b0 * L_SEQ * 128,
          128, (long)16384 * 128, MT, 512, DIMM,
          tids + (size_t)b0 * L_SEQ, t);
    }
  }
}